// Round 11
// baseline (4590.001 us; speedup 1.0000x reference)
//
#include <hip/hip_runtime.h>
#include <math.h>

constexpr int B = 2;
constexpr int F = 2112;
constexpr int D = 1024;
constexpr int H = 8;
constexpr int DH = 64;
constexpr int INNER = H * DH;      // 512
constexpr int NL = 721;
constexpr int NL_PAD = 768;
constexpr int MLAT = B * NL;       // 1442
constexpr int MLAT_PAD = 1536;
constexpr int VD = 64;
constexpr int DEPTH = 6;
constexpr int FN = F + NL;         // 2833
constexpr int FN_PAD = 2880;       // 45 * 64
constexpr int NBH = B * H;         // 16
constexpr int SKV = 4;             // attention KV splits
constexpr int MX = B * F;          // 4224
constexpr int MEGA_G = 512;        // 2 blocks/CU x 256 CUs, guaranteed by launch_bounds(256,2)
constexpr float EPS = 1e-5f;

typedef __bf16 bf16x8 __attribute__((ext_vector_type(8)));
typedef float  f32x4  __attribute__((ext_vector_type(4)));

static __device__ __forceinline__ unsigned short f2bf(float f)
{
    union { float f; unsigned int u; } x; x.f = f;
    unsigned int r = x.u + 0x7FFFu + ((x.u >> 16) & 1u);   // RNE
    return (unsigned short)(r >> 16);
}
static __device__ __forceinline__ float bf2f(unsigned short u)
{
    union { unsigned int i; float f; } x; x.i = ((unsigned int)u) << 16; return x.f;
}

// ---------------- block reduce (sum, sumsq) over 256 threads ----------------
__device__ __forceinline__ void block_reduce_2(float& s, float& ss, float* red)
{
#pragma unroll
    for (int off = 32; off; off >>= 1) {
        s  += __shfl_xor(s, off);
        ss += __shfl_xor(ss, off);
    }
    int wv = threadIdx.x >> 6;
    if ((threadIdx.x & 63) == 0) { red[wv] = s; red[4 + wv] = ss; }
    __syncthreads();
    s  = red[0] + red[1] + red[2] + red[3];
    ss = red[4] + red[5] + red[6] + red[7];
}

// ------- x + spatial_emb + frame_emb, then row-normalize -> bf16 xhat -------
__global__ __launch_bounds__(256) void emb_ln_kernel(
    const float* __restrict__ x, const float* __restrict__ sp_emb,
    const float* __restrict__ fr_emb, unsigned short* __restrict__ xhat)
{
    __shared__ float red[8];
    int r = blockIdx.x;            // r = b*F + j
    int j = r % F;
    int t = threadIdx.x;
    const float4* xr = (const float4*)(x + (long)r * D);
    int spr = (j < VD) ? j : VD;
    int frr = (j < VD) ? 0 : (j - VD + 1);
    const float4* sp4 = (const float4*)(sp_emb + (long)spr * D);
    const float4* fr4 = (const float4*)(fr_emb + (long)frr * D);
    float4 v = xr[t], a = sp4[t], c = fr4[t];
    v.x += a.x + c.x; v.y += a.y + c.y; v.z += a.z + c.z; v.w += a.w + c.w;
    float s  = v.x + v.y + v.z + v.w;
    float ss = v.x*v.x + v.y*v.y + v.z*v.z + v.w*v.w;
    block_reduce_2(s, ss, red);
    float mean = s * (1.0f / D);
    float var  = ss * (1.0f / D) - mean * mean;
    float rstd = rsqrtf(var + EPS);
    ushort4 o;
    o.x = f2bf((v.x - mean) * rstd);
    o.y = f2bf((v.y - mean) * rstd);
    o.z = f2bf((v.z - mean) * rstd);
    o.w = f2bf((v.w - mean) * rstd);
    ((ushort4*)(xhat + (long)r * D))[t] = o;
}

// ------------------------ final LN with affine -> out ------------------------
__global__ __launch_bounds__(256) void final_ln_kernel(
    const float* __restrict__ in, const float* __restrict__ g,
    const float* __restrict__ b, float* __restrict__ out)
{
    __shared__ float red[8];
    int r = blockIdx.x;
    int t = threadIdx.x;
    float4 v = ((const float4*)(in + (long)r * D))[t];
    float s  = v.x + v.y + v.z + v.w;
    float ss = v.x*v.x + v.y*v.y + v.z*v.z + v.w*v.w;
    block_reduce_2(s, ss, red);
    float mean = s * (1.0f / D);
    float var  = ss * (1.0f / D) - mean * mean;
    float rstd = rsqrtf(var + EPS);
    float4 g4 = ((const float4*)g)[t];
    float4 b4 = ((const float4*)b)[t];
    float4 o;
    o.x = (v.x - mean) * rstd * g4.x + b4.x;
    o.y = (v.y - mean) * rstd * g4.y + b4.y;
    o.z = (v.z - mean) * rstd * g4.z + b4.z;
    o.w = (v.w - mean) * rstd * g4.w + b4.w;
    ((float4*)(out + (long)r * D))[t] = o;
}

// ------------- lat init (broadcast latents) + barrier counter zero ----------
__global__ __launch_bounds__(256) void lat_init_kernel(
    const float* __restrict__ latents, float* __restrict__ lat,
    unsigned* __restrict__ cnt)
{
    if (blockIdx.x == 0 && threadIdx.x == 0) *cnt = 0u;
    int r = blockIdx.x;
    int i = r % NL;
    int t = threadIdx.x;
    ((float4*)(lat + (long)r * D))[t] = ((const float4*)(latents + (long)i * D))[t];
}

// ---------- weight convert via LDS transpose (coalesced both sides) ----------
// dst per layer: [ wlatT(1536x1024) | woT(1024x512) | f1T(4096x1024) | f2T(1024x4096) ]
constexpr long WL_LAT = 1536L * 1024;
constexpr long WL_WO  = 1024L * 512;
constexpr long WL_F1  = 4096L * 1024;
constexpr long WL_F2  = 1024L * 4096;
constexpr long WL_SZ  = WL_LAT + WL_WO + WL_F1 + WL_F2;   // 10,485,760 ushorts

__device__ __forceinline__ void conv_tile64(
    const float* __restrict__ src, unsigned short* __restrict__ dst,
    int Kd, int Nd, int tn, int tk, float* lds)
{
    int t = threadIdx.x;
    int n0 = tn * 64, k0 = tk * 64;
#pragma unroll
    for (int p = 0; p < 16; ++p) {
        int idx = p * 256 + t;
        int kr = idx >> 6, nc = idx & 63;
        lds[nc * 65 + kr] = src[(long)(k0 + kr) * Nd + n0 + nc];
    }
    __syncthreads();
#pragma unroll
    for (int p = 0; p < 2; ++p) {
        int nl_ = p * 32 + (t >> 3);
        int kc  = t & 7;
        unsigned short u[8];
#pragma unroll
        for (int j = 0; j < 8; ++j)
            u[j] = f2bf(lds[nl_ * 65 + kc * 8 + j]);
        *(uint4*)(dst + (long)(n0 + nl_) * Kd + k0 + kc * 8) = *(uint4*)u;
    }
}

__global__ __launch_bounds__(256) void wt_conv_all_kernel(
    const float* __restrict__ wq, const float* __restrict__ wkv,
    const float* __restrict__ wo, const float* __restrict__ ffw1,
    const float* __restrict__ ffw2, unsigned short* __restrict__ wbuf)
{
    __shared__ float lds[64 * 65];
    int l = blockIdx.y;
    unsigned short* wl = wbuf + (long)l * WL_SZ;
    const float* wq_l   = wq   + (long)l * D * INNER;
    const float* wkv_l  = wkv  + (long)l * D * 2 * INNER;
    const float* wo_l   = wo   + (long)l * INNER * D;
    const float* ffw1_l = ffw1 + (long)l * D * 4 * D;
    const float* ffw2_l = ffw2 + (long)l * 4 * D * D;

    int T = blockIdx.x;
    if (T < 128) {
        conv_tile64(wq_l, wl, D, INNER, T & 7, T >> 3, lds);
    } else if (T < 384) {
        int Ti = T - 128;
        conv_tile64(wkv_l, wl + 512L * D, D, 2 * INNER, Ti & 15, Ti >> 4, lds);
    } else if (T < 512) {
        int Ti = T - 384;
        conv_tile64(wo_l, wl + WL_LAT, INNER, D, Ti & 15, Ti >> 4, lds);
    } else if (T < 1536) {
        int Ti = T - 512;
        conv_tile64(ffw1_l, wl + WL_LAT + WL_WO, D, 4 * D, Ti & 63, Ti >> 6, lds);
    } else {
        int Ti = T - 1536;
        conv_tile64(ffw2_l, wl + WL_LAT + WL_WO + WL_F1, 4 * D, D, Ti & 15, Ti >> 4, lds);
    }
}

// ------------------------ grid barrier (device scope) ------------------------
// Co-residency is guaranteed by __launch_bounds__(256,2) + grid == 512 on 256
// CUs. Guard bails after ~6.7e7 spins: a broken protocol fails fast (wrong
// output) instead of a HW timeout.
__device__ __forceinline__ void grid_bar(unsigned* cnt, unsigned& epoch, int G)
{
    __syncthreads();
    if (threadIdx.x == 0) {
        __threadfence();                      // release: prior writes visible
        atomicAdd(cnt, 1u);
        epoch += (unsigned)G;
        int guard = 0;
        while (__hip_atomic_load(cnt, __ATOMIC_RELAXED, __HIP_MEMORY_SCOPE_AGENT) < epoch) {
            __builtin_amdgcn_s_sleep(2);
            if (++guard > (1 << 26)) break;
        }
        __threadfence();                      // acquire: others' writes visible
    }
    __syncthreads();
}

// --------------------- per-wave LN / affine row helpers ----------------------
__device__ __forceinline__ void wave_ln_aff(
    const float* __restrict__ in, const float* __restrict__ g,
    const float* __restrict__ b, unsigned short* __restrict__ out, int lane)
{
    float4 v[4];
    float s = 0.f, ss = 0.f;
#pragma unroll
    for (int p = 0; p < 4; ++p) {
        v[p] = ((const float4*)in)[lane + p * 64];
        s  += v[p].x + v[p].y + v[p].z + v[p].w;
        ss += v[p].x*v[p].x + v[p].y*v[p].y + v[p].z*v[p].z + v[p].w*v[p].w;
    }
#pragma unroll
    for (int off = 32; off; off >>= 1) {
        s  += __shfl_xor(s, off);
        ss += __shfl_xor(ss, off);
    }
    float mean = s * (1.0f / D);
    float var  = ss * (1.0f / D) - mean * mean;
    float rstd = rsqrtf(var + EPS);
#pragma unroll
    for (int p = 0; p < 4; ++p) {
        float4 g4 = ((const float4*)g)[lane + p * 64];
        float4 b4 = ((const float4*)b)[lane + p * 64];
        ushort4 o;
        o.x = f2bf((v[p].x - mean) * rstd * g4.x + b4.x);
        o.y = f2bf((v[p].y - mean) * rstd * g4.y + b4.y);
        o.z = f2bf((v[p].z - mean) * rstd * g4.z + b4.z);
        o.w = f2bf((v[p].w - mean) * rstd * g4.w + b4.w);
        ((ushort4*)out)[lane + p * 64] = o;
    }
}

__device__ __forceinline__ void wave_aff(
    const unsigned short* __restrict__ in, const float* __restrict__ g,
    const float* __restrict__ b, unsigned short* __restrict__ out, int lane)
{
#pragma unroll
    for (int p = 0; p < 4; ++p) {
        ushort4 u4 = ((const ushort4*)in)[lane + p * 64];
        float4 g4 = ((const float4*)g)[lane + p * 64];
        float4 b4 = ((const float4*)b)[lane + p * 64];
        ushort4 o;
        o.x = f2bf(bf2f(u4.x) * g4.x + b4.x);
        o.y = f2bf(bf2f(u4.y) * g4.y + b4.y);
        o.z = f2bf(bf2f(u4.z) * g4.z + b4.z);
        o.w = f2bf(bf2f(u4.w) * g4.w + b4.w);
        ((ushort4*)out)[lane + p * 64] = o;
    }
}

// --------------------- wave-tile bf16 GEMM core ------------------------------
__device__ __forceinline__ void load_set(
    const unsigned short* __restrict__ ap, const unsigned short* __restrict__ bp,
    long rs, int ko, bf16x8 (&av)[4], bf16x8 (&bv)[4])
{
#pragma unroll
    for (int q = 0; q < 4; ++q) {
        av[q] = *(const bf16x8*)(ap + q * rs + ko);
        bv[q] = *(const bf16x8*)(bp + q * rs + ko);
    }
}

__device__ __forceinline__ void mfma_set(
    const bf16x8 (&av)[4], const bf16x8 (&bv)[4], f32x4 (&acc)[4][4])
{
#pragma unroll
    for (int mm = 0; mm < 4; ++mm)
#pragma unroll
        for (int nn = 0; nn < 4; ++nn)
            acc[mm][nn] = __builtin_amdgcn_mfma_f32_16x16x32_bf16(av[mm], bv[nn], acc[mm][nn], 0, 0, 0);
}

__device__ __forceinline__ void gemm_core(
    const unsigned short* __restrict__ ap, const unsigned short* __restrict__ bp,
    long rs, int Kc, f32x4 (&acc)[4][4])
{
    bf16x8 aC[4], bC[4], aN[4], bN[4];
    load_set(ap, bp, rs, 0, aC, bC);
    for (int ko = 0; ko < Kc; ko += 64) {
        load_set(ap, bp, rs, ko + 32, aN, bN);
        mfma_set(aC, bC, acc);
        if (ko + 64 < Kc)
            load_set(ap, bp, rs, ko + 64, aC, bC);
        mfma_set(aN, bN, acc);
    }
}

// -------------------------- mega-kernel stage tiles --------------------------
__device__ void qkv_tile(int T,
    const unsigned short* __restrict__ la, const unsigned short* __restrict__ xa,
    const unsigned short* __restrict__ wlatT,
    unsigned short* __restrict__ qb, unsigned short* __restrict__ kb,
    unsigned short* __restrict__ vt, int lane)
{
    int lr = lane & 15, lg = lane >> 4;
    const unsigned short* A;
    const unsigned short* Bt;
    long m0, n0;
    int M, rpb, joff, qcols;
    if (T < 552) {
        int bm = T % 23, bn = T / 23;
        A = la; Bt = wlatT;
        m0 = (long)bm * 64; n0 = (long)bn * 64;
        M = MLAT; rpb = NL; joff = F; qcols = 512;
    } else {
        int Ti = T - 552;
        int bm = Ti % 66, bn = Ti / 66;
        A = xa; Bt = wlatT + 512L * D;
        m0 = (long)bm * 64; n0 = (long)bn * 64;
        M = MX; rpb = F; joff = 0; qcols = 0;
    }

    const unsigned short* ap = A  + (m0 + lr) * D + lg * 8;
    const unsigned short* bp = Bt + (n0 + lr) * D + lg * 8;
    f32x4 acc[4][4] = {};
    gemm_core(ap, bp, 16L * D, D, acc);

#pragma unroll
    for (int mm = 0; mm < 4; ++mm) {
        long ar0 = m0 + mm * 16 + lg * 4;
        if (ar0 >= M) continue;
#pragma unroll
        for (int nn = 0; nn < 4; ++nn) {
            long col = n0 + nn * 16 + lr;
            f32x4 v = acc[mm][nn];
            if (col < qcols) {
#pragma unroll
                for (int r = 0; r < 4; ++r) {
                    long ar = ar0 + r;
                    if (ar < M) {
                        int bb = ar >= NL;
                        long i = ar - (bb ? NL : 0);
                        qb[((long)bb * NL_PAD + i) * INNER + col] = f2bf(v[r] * 0.125f);
                    }
                }
            } else {
                int c = (int)col - qcols;    // 0..1023
                if (c < 512) {               // K-part
#pragma unroll
                    for (int r = 0; r < 4; ++r) {
                        long ar = ar0 + r;
                        if (ar < M) {
                            int bb = ar >= rpb;
                            long i = ar - (bb ? rpb : 0);
                            kb[((long)bb * FN_PAD + joff + i) * INNER + c] = f2bf(v[r]);
                        }
                    }
                } else {                     // V-part (transposed store)
                    int d = c - 512;
                    int bb0 = ar0 >= rpb;
                    int bb3 = (ar0 + 3) >= rpb;
                    long i0 = ar0 - (bb0 ? rpb : 0);
                    long j0 = joff + i0;
                    if ((ar0 + 3 < M) && (bb0 == bb3) && ((j0 & 3) == 0)) {
                        ushort4 pk;
                        pk.x = f2bf(v[0]); pk.y = f2bf(v[1]);
                        pk.z = f2bf(v[2]); pk.w = f2bf(v[3]);
                        *(ushort4*)(vt + ((long)bb0 * INNER + d) * FN_PAD + j0) = pk;
                    } else {
#pragma unroll
                        for (int r = 0; r < 4; ++r) {
                            long ar = ar0 + r;
                            if (ar < M) {
                                int bb = ar >= rpb;
                                long i = ar - (bb ? rpb : 0);
                                vt[((long)bb * INNER + d) * FN_PAD + joff + i] = f2bf(v[r]);
                            }
                        }
                    }
                }
            }
        }
    }
}

__device__ void gemm_tile_resa(
    const unsigned short* __restrict__ A, const unsigned short* __restrict__ Bt,
    float* __restrict__ C, int M, int K, int Kc, int ldc,
    int bm, int bn, int kz, int lane)
{
    int lr = lane & 15, lg = lane >> 4;
    long m0 = (long)bm * 64, n0 = (long)bn * 64;
    int k0 = kz * Kc;
    const unsigned short* ap = A  + (m0 + lr) * K + k0 + lg * 8;
    const unsigned short* bp = Bt + (n0 + lr) * K + k0 + lg * 8;
    f32x4 acc[4][4] = {};
    gemm_core(ap, bp, 16L * K, Kc, acc);
#pragma unroll
    for (int mm = 0; mm < 4; ++mm) {
        long ar0 = m0 + mm * 16 + lg * 4;
        if (ar0 >= M) continue;
#pragma unroll
        for (int nn = 0; nn < 4; ++nn) {
            long col = n0 + nn * 16 + lr;
            f32x4 v = acc[mm][nn];
#pragma unroll
            for (int r = 0; r < 4; ++r)
                if (ar0 + r < M)
                    unsafeAtomicAdd(&C[(ar0 + r) * (long)ldc + col], v[r]);
        }
    }
}

__device__ void gemm_tile_gelu(
    const unsigned short* __restrict__ A, const unsigned short* __restrict__ Bt,
    unsigned short* __restrict__ C, int M, int K, int ldc,
    int bm, int bn, int lane)
{
    int lr = lane & 15, lg = lane >> 4;
    long m0 = (long)bm * 64, n0 = (long)bn * 64;
    const unsigned short* ap = A  + (m0 + lr) * K + lg * 8;
    const unsigned short* bp = Bt + (n0 + lr) * K + lg * 8;
    f32x4 acc[4][4] = {};
    gemm_core(ap, bp, 16L * K, K, acc);
#pragma unroll
    for (int mm = 0; mm < 4; ++mm) {
        long ar0 = m0 + mm * 16 + lg * 4;
        if (ar0 >= M) continue;
#pragma unroll
        for (int nn = 0; nn < 4; ++nn) {
            long col = n0 + nn * 16 + lr;
            f32x4 v = acc[mm][nn];
#pragma unroll
            for (int r = 0; r < 4; ++r)
                if (ar0 + r < M) {
                    float val = v[r];
                    val = 0.5f * val * (1.0f + erff(val * 0.70710678118654752f));
                    C[(ar0 + r) * (long)ldc + col] = f2bf(val);
                }
        }
    }
}

__device__ void attn_unit(int u,
    const unsigned short* __restrict__ qb, const unsigned short* __restrict__ kb,
    const unsigned short* __restrict__ vt, const int* __restrict__ split,
    float* __restrict__ po, float* __restrict__ pml,
    unsigned short* pl, int lane)
{
    int q16  = u % 48;
    int bh   = (u / 48) % NBH;
    int sidx = u / (48 * NBH);
    int q0 = q16 * 16;
    if (q0 >= NL) return;
    int b = bh >> 3, h = bh & 7;

    int lr = lane & 15;
    int lg = lane >> 4;

    bf16x8 qa0, qa1;
    {
        const unsigned short* qrow = qb + ((long)b * NL_PAD + q0 + lr) * INNER + h * 64;
        qa0 = *(const bf16x8*)(qrow + lg * 8);
        qa1 = *(const bf16x8*)(qrow + 32 + lg * 8);
    }

    f32x4 oacc[4] = {{0,0,0,0},{0,0,0,0},{0,0,0,0},{0,0,0,0}};
    float m[4]    = {-1e30f, -1e30f, -1e30f, -1e30f};
    float lsum[4] = {0.f, 0.f, 0.f, 0.f};

    int sp = split[b];
    if (sp < 0) sp = 0;
    if (sp > F) sp = F;
    int ntx = (sp + 63) >> 6;
    int ntot = ntx + 12;
    int t0 = (ntot * sidx) / SKV;
    int t1 = (ntot * (sidx + 1)) / SKV;

    for (int t = t0; t < t1; ++t) {
        int j0, limit;
        if (t < ntx) { j0 = t * 64;             limit = sp; }
        else         { j0 = F + (t - ntx) * 64; limit = FN; }

        f32x4 s[4] = {{0,0,0,0},{0,0,0,0},{0,0,0,0},{0,0,0,0}};
        const unsigned short* kbase =
            kb + ((long)b * FN_PAD + j0 + lr) * INNER + h * 64 + lg * 8;
#pragma unroll
        for (int st = 0; st < 4; ++st) {
            bf16x8 kf0 = *(const bf16x8*)(kbase + (long)st * 16 * INNER);
            bf16x8 kf1 = *(const bf16x8*)(kbase + (long)st * 16 * INNER + 32);
            s[st] = __builtin_amdgcn_mfma_f32_16x16x32_bf16(qa0, kf0, s[st], 0, 0, 0);
            s[st] = __builtin_amdgcn_mfma_f32_16x16x32_bf16(qa1, kf1, s[st], 0, 0, 0);
        }

        if (j0 + 64 > limit) {
#pragma unroll
            for (int st = 0; st < 4; ++st) {
                bool valid = (j0 + st * 16 + lr) < limit;
#pragma unroll
                for (int r = 0; r < 4; ++r)
                    s[st][r] = valid ? s[st][r] : -1e30f;
            }
        }

        float tm[4];
#pragma unroll
        for (int r = 0; r < 4; ++r)
            tm[r] = fmaxf(fmaxf(s[0][r], s[1][r]), fmaxf(s[2][r], s[3][r]));
#pragma unroll
        for (int off = 1; off < 16; off <<= 1) {
#pragma unroll
            for (int r = 0; r < 4; ++r)
                tm[r] = fmaxf(tm[r], __shfl_xor(tm[r], off));
        }
        float cr[4];
#pragma unroll
        for (int r = 0; r < 4; ++r) {
            float mn = fmaxf(m[r], tm[r]);
            cr[r] = __expf(m[r] - mn);
            m[r]  = mn;
        }
#pragma unroll
        for (int st = 0; st < 4; ++st)
#pragma unroll
            for (int r = 0; r < 4; ++r)
                s[st][r] = __expf(s[st][r] - m[r]);
        float ts[4];
#pragma unroll
        for (int r = 0; r < 4; ++r)
            ts[r] = (s[0][r] + s[1][r]) + (s[2][r] + s[3][r]);
#pragma unroll
        for (int off = 1; off < 16; off <<= 1) {
#pragma unroll
            for (int r = 0; r < 4; ++r)
                ts[r] += __shfl_xor(ts[r], off);
        }
#pragma unroll
        for (int r = 0; r < 4; ++r)
            lsum[r] = lsum[r] * cr[r] + ts[r];
#pragma unroll
        for (int nst = 0; nst < 4; ++nst)
#pragma unroll
            for (int r = 0; r < 4; ++r)
                oacc[nst][r] *= cr[r];

#pragma unroll
        for (int st = 0; st < 4; ++st)
#pragma unroll
            for (int r = 0; r < 4; ++r) {
                int row  = lg * 4 + r;
                int col  = st * 16 + lr;
                int byte = (row * 128 + col * 2) ^ ((row & 7) << 4);
                *(unsigned short*)((char*)pl + byte) = f2bf(s[st][r]);
            }

#pragma unroll
        for (int kk = 0; kk < 2; ++kk) {
            int row  = lr;
            int byte = (row * 128 + kk * 64 + lg * 16) ^ ((row & 7) << 4);
            bf16x8 pa = *(const bf16x8*)((char*)pl + byte);
#pragma unroll
            for (int nst = 0; nst < 4; ++nst) {
                const unsigned short* vp =
                    vt + ((long)bh * DH + nst * 16 + lr) * FN_PAD + j0 + kk * 32 + lg * 8;
                bf16x8 vf = *(const bf16x8*)vp;
                oacc[nst] = __builtin_amdgcn_mfma_f32_16x16x32_bf16(pa, vf, oacc[nst], 0, 0, 0);
            }
        }
    }

    long base = ((long)sidx * NBH + bh) * NL_PAD;
#pragma unroll
    for (int nst = 0; nst < 4; ++nst)
#pragma unroll
        for (int r = 0; r < 4; ++r) {
            int row = q0 + lg * 4 + r;
            if (row < NL)
                po[(base + row) * DH + nst * 16 + lr] = oacc[nst][r];
        }
    if (lr == 0) {
#pragma unroll
        for (int r = 0; r < 4; ++r) {
            int row = q0 + lg * 4 + r;
            if (row < NL) {
                pml[(base + row) * 2 + 0] = m[r];
                pml[(base + row) * 2 + 1] = lsum[r];
            }
        }
    }
}

__device__ void combine_unit(int u,
    const float* __restrict__ po, const float* __restrict__ pml,
    unsigned short* __restrict__ o, int lane)
{
    int bh = u / NL;
    int i  = u - bh * NL;
    int b = bh >> 3, h = bh & 7;

    float m = -1e30f, l = 0.0f, acc = 0.0f;
#pragma unroll
    for (int s = 0; s < SKV; ++s) {
        long base = ((long)s * NBH + bh) * NL_PAD + i;
        float ms = pml[base * 2 + 0];
        float ls = pml[base * 2 + 1];
        float os = po[base * DH + lane];
        float mn = fmaxf(m, ms);
        float c1 = __expf(m - mn);
        float c2 = __expf(ms - mn);
        acc = acc * c1 + os * c2;
        l   = l * c1 + ls * c2;
        m   = mn;
    }
    o[((long)b * NL + i) * INNER + h * 64 + lane] = f2bf(acc / l);
}

// ------------------------------ THE MEGA KERNEL ------------------------------
// __launch_bounds__(256, 2): min 2 waves/EU -> compiler guarantees resources
// for >= 2 blocks/CU. Grid = MEGA_G = 512 = 2 x 256 CUs -> all blocks
// co-resident by construction (total capacity >= grid size).
__global__ __launch_bounds__(256, 2) void mega_kernel(
    const unsigned short* __restrict__ xhat, float* __restrict__ lat,
    const float* __restrict__ nm_g, const float* __restrict__ nm_b,
    const float* __restrict__ nl_g, const float* __restrict__ nl_b,
    const float* __restrict__ ffn_g, const float* __restrict__ ffn_b,
    const unsigned short* __restrict__ wbuf,
    unsigned short* __restrict__ xa, unsigned short* __restrict__ la,
    unsigned short* __restrict__ fa, unsigned short* __restrict__ h1b,
    unsigned short* __restrict__ ob, unsigned short* __restrict__ qb,
    unsigned short* __restrict__ kb, unsigned short* __restrict__ vt,
    float* __restrict__ po, float* __restrict__ pml,
    const int* __restrict__ split, unsigned* __restrict__ cnt)
{
    __shared__ unsigned short p_lds[4][16 * 64];
    const int G = MEGA_G;
    int w = threadIdx.x >> 6, lane = threadIdx.x & 63;
    int gw = blockIdx.x * 4 + w;
    int GW = G * 4;
    unsigned epoch = 0;

    for (int l = 0; l < DEPTH; ++l) {
        const unsigned short* wl    = wbuf + (long)l * WL_SZ;
        const unsigned short* wlatT = wl;
        const unsigned short* woT   = wl + WL_LAT;
        const unsigned short* f1T   = wl + WL_LAT + WL_WO;
        const unsigned short* f2T   = wl + WL_LAT + WL_WO + WL_F1;

        // S0: xa = xhat*nm+b (MX rows), la = LN(lat)*nl+b (MLAT rows)
        for (int u = gw; u < MX + MLAT; u += GW) {
            if (u < MX)
                wave_aff(xhat + (long)u * D, nm_g + (long)l * D, nm_b + (long)l * D,
                         xa + (long)u * D, lane);
            else {
                int r = u - MX;
                wave_ln_aff(lat + (long)r * D, nl_g + (long)l * D, nl_b + (long)l * D,
                            la + (long)r * D, lane);
            }
        }
        grid_bar(cnt, epoch, G);

        // S1: q + kv(lat) + kv(x) projection, 1608 wave-tiles
        for (int u = gw; u < 1608; u += GW)
            qkv_tile(u, la, xa, wlatT, qb, kb, vt, lane);
        grid_bar(cnt, epoch, G);

        // S2: attention partials, 48*16*SKV wave-units
        for (int u = gw; u < 48 * NBH * SKV; u += GW)
            attn_unit(u, qb, kb, vt, split, po, pml, p_lds[w], lane);
        grid_bar(cnt, epoch, G);

        // S3: combine partials -> ob
        for (int u = gw; u < NBH * NL; u += GW)
            combine_unit(u, po, pml, ob, lane);
        grid_bar(cnt, epoch, G);

        // S4: lat += ob @ wo (split-K 4), 23*16*4 tiles
        for (int u = gw; u < 23 * 16 * 4; u += GW) {
            int bm = u % 23, bn = (u / 23) & 15, kz = u / 368;
            gemm_tile_resa(ob, woT, lat, MLAT, INNER, 128, D, bm, bn, kz, lane);
        }
        grid_bar(cnt, epoch, G);

        // S5: fa = LN(lat)*ffn_g+ffn_b
        for (int u = gw; u < MLAT; u += GW)
            wave_ln_aff(lat + (long)u * D, ffn_g + (long)l * D, ffn_b + (long)l * D,
                        fa + (long)u * D, lane);
        grid_bar(cnt, epoch, G);

        // S6: h1 = gelu(fa @ ffw1), 23*64 tiles
        for (int u = gw; u < 23 * 64; u += GW) {
            int bm = u % 23, bn = u / 23;
            gemm_tile_gelu(fa, f1T, h1b, MLAT, D, 4 * D, bm, bn, lane);
        }
        grid_bar(cnt, epoch, G);

        // S7: lat += h1 @ ffw2 (split-K 8), 23*16*8 tiles
        for (int u = gw; u < 23 * 16 * 8; u += GW) {
            int bm = u % 23, bn = (u / 23) & 15, kz = u / 368;
            gemm_tile_resa(h1b, f2T, lat, MLAT, 4 * D, 512, D, bm, bn, kz, lane);
        }
        grid_bar(cnt, epoch, G);
    }
}

// ------------------------------- host side ----------------------------------
extern "C" void kernel_launch(void* const* d_in, const int* in_sizes, int n_in,
                              void* d_out, int out_size, void* d_ws, size_t ws_size,
                              hipStream_t stream)
{
    const float* x        = (const float*)d_in[0];
    const int*   split    = (const int*)d_in[1];
    const float* latents  = (const float*)d_in[2];
    const float* sp_emb   = (const float*)d_in[3];
    const float* fr_emb   = (const float*)d_in[4];
    const float* nm_g     = (const float*)d_in[5];
    const float* nm_b     = (const float*)d_in[6];
    const float* nl_g     = (const float*)d_in[7];
    const float* nl_b     = (const float*)d_in[8];
    const float* wq       = (const float*)d_in[9];
    const float* wkv      = (const float*)d_in[10];
    const float* wo       = (const float*)d_in[11];
    const float* ffn_g    = (const float*)d_in[12];
    const float* ffn_b    = (const float*)d_in[13];
    const float* ffw1     = (const float*)d_in[14];
    const float* ffw2     = (const float*)d_in[15];
    const float* final_g  = (const float*)d_in[16];
    const float* final_b  = (const float*)d_in[17];
    float* out = (float*)d_out;

    // ---- cursor-based workspace layout ----
    char* cur = (char*)d_ws;
    auto alloc = [&](size_t bytes) {
        void* p = (void*)cur;
        cur += (bytes + 255) & ~(size_t)255;
        return p;
    };

    unsigned short* xhat = (unsigned short*)alloc((long)MX * D * 2);
    float* lat  = (float*)alloc((long)B * NL * D * 4);
    unsigned short* la  = (unsigned short*)alloc((long)MLAT_PAD * D * 2);
    unsigned short* fa  = (unsigned short*)alloc((long)MLAT_PAD * D * 2);
    unsigned short* h1b = (unsigned short*)alloc((long)MLAT_PAD * 4 * D * 2);
    unsigned short* ob  = (unsigned short*)alloc((long)MLAT_PAD * INNER * 2);
    unsigned short* qb  = (unsigned short*)alloc((long)B * NL_PAD * INNER * 2);
    unsigned short* kb  = (unsigned short*)alloc((long)B * FN_PAD * INNER * 2);
    unsigned short* vt  = (unsigned short*)alloc((long)B * FN_PAD * INNER * 2);
    unsigned short* xa  = (unsigned short*)alloc((long)MX * D * 2);
    float* po  = (float*)alloc((long)SKV * NBH * NL_PAD * DH * 4);
    float* pml = (float*)alloc((long)SKV * NBH * NL_PAD * 2 * 4);
    unsigned* cnt = (unsigned*)alloc(256);
    unsigned short* wbuf = (unsigned short*)alloc((size_t)6 * WL_SZ * 2);

    emb_ln_kernel<<<MX, 256, 0, stream>>>(x, sp_emb, fr_emb, xhat);
    lat_init_kernel<<<B * NL, 256, 0, stream>>>(latents, lat, cnt);
    wt_conv_all_kernel<<<dim3(2560, 6), 256, 0, stream>>>(wq, wkv, wo, ffw1, ffw2, wbuf);

    mega_kernel<<<MEGA_G, 256, 0, stream>>>(
        xhat, lat, nm_g, nm_b, nl_g, nl_b, ffn_g, ffn_b, wbuf,
        xa, la, fa, h1b, ob, qb, kb, vt, po, pml, split, cnt);

    final_ln_kernel<<<MLAT, 256, 0, stream>>>(lat, final_g, final_b, out);
}

// Round 12
// 1890.438 us; speedup vs baseline: 2.4280x; 2.4280x over previous
//
#include <hip/hip_runtime.h>
#include <math.h>

constexpr int B = 2;
constexpr int F = 2112;
constexpr int D = 1024;
constexpr int H = 8;
constexpr int DH = 64;
constexpr int INNER = H * DH;      // 512
constexpr int NL = 721;
constexpr int NL_PAD = 768;
constexpr int MLAT = B * NL;       // 1442
constexpr int MLAT_PAD = 1536;
constexpr int VD = 64;
constexpr int DEPTH = 6;
constexpr int FN = F + NL;         // 2833
constexpr int FN_PAD = 2880;       // 45 * 64
constexpr int NBH = B * H;         // 16
constexpr int SKVMAX = 8;
constexpr int MX = B * F;          // 4224
constexpr float EPS = 1e-5f;

typedef __bf16 bf16x8 __attribute__((ext_vector_type(8)));
typedef float  f32x4  __attribute__((ext_vector_type(4)));

static __device__ __forceinline__ unsigned short f2bf(float f)
{
    union { float f; unsigned int u; } x; x.f = f;
    unsigned int r = x.u + 0x7FFFu + ((x.u >> 16) & 1u);   // RNE
    return (unsigned short)(r >> 16);
}
static __device__ __forceinline__ float bf2f(unsigned short u)
{
    union { unsigned int i; float f; } x; x.i = ((unsigned int)u) << 16; return x.f;
}

// XCD-chunked bijective block->tile mapping. Requires nt % 8 == 0.
// HW round-robins consecutive blockIdx across the 8 XCDs; this gives each XCD
// a CONTIGUOUS tile range so same-panel tiles share one L2.
static __device__ __forceinline__ int xcd_swz(int b, int nt)
{
    return (b & 7) * (nt >> 3) + (b >> 3);
}

// ---------------- block reduce (sum, sumsq) over 256 threads ----------------
__device__ __forceinline__ void block_reduce_2(float& s, float& ss, float* red)
{
#pragma unroll
    for (int off = 32; off; off >>= 1) {
        s  += __shfl_xor(s, off);
        ss += __shfl_xor(ss, off);
    }
    int wv = threadIdx.x >> 6;
    if ((threadIdx.x & 63) == 0) { red[wv] = s; red[4 + wv] = ss; }
    __syncthreads();
    s  = red[0] + red[1] + red[2] + red[3];
    ss = red[4] + red[5] + red[6] + red[7];
}

// ------- x + spatial_emb + frame_emb, then row-normalize -> bf16 xhat -------
__global__ __launch_bounds__(256) void emb_ln_kernel(
    const float* __restrict__ x, const float* __restrict__ sp_emb,
    const float* __restrict__ fr_emb, unsigned short* __restrict__ xhat)
{
    __shared__ float red[8];
    int r = blockIdx.x;            // r = b*F + j
    int j = r % F;
    int t = threadIdx.x;
    const float4* xr = (const float4*)(x + (long)r * D);
    int spr = (j < VD) ? j : VD;
    int frr = (j < VD) ? 0 : (j - VD + 1);
    const float4* sp4 = (const float4*)(sp_emb + (long)spr * D);
    const float4* fr4 = (const float4*)(fr_emb + (long)frr * D);
    float4 v = xr[t], a = sp4[t], c = fr4[t];
    v.x += a.x + c.x; v.y += a.y + c.y; v.z += a.z + c.z; v.w += a.w + c.w;
    float s  = v.x + v.y + v.z + v.w;
    float ss = v.x*v.x + v.y*v.y + v.z*v.z + v.w*v.w;
    block_reduce_2(s, ss, red);
    float mean = s * (1.0f / D);
    float var  = ss * (1.0f / D) - mean * mean;
    float rstd = rsqrtf(var + EPS);
    ushort4 o;
    o.x = f2bf((v.x - mean) * rstd);
    o.y = f2bf((v.y - mean) * rstd);
    o.z = f2bf((v.z - mean) * rstd);
    o.w = f2bf((v.w - mean) * rstd);
    ((ushort4*)(xhat + (long)r * D))[t] = o;
}

// ----- fused per-layer A-prep: xa = xhat*nm_g+nm_b ; la = LN(lat)*nl_g+nl_b --
__global__ __launch_bounds__(256) void prep_a_kernel(
    const unsigned short* __restrict__ xhat, const float* __restrict__ lat,
    const float* __restrict__ nmg, const float* __restrict__ nmb,
    const float* __restrict__ nlg, const float* __restrict__ nlb,
    unsigned short* __restrict__ xa, unsigned short* __restrict__ la)
{
    __shared__ float red[8];
    int r = blockIdx.x;
    int t = threadIdx.x;
    if (r < MX) {
        ushort4 u4 = ((const ushort4*)(xhat + (long)r * D))[t];
        float4 g4 = ((const float4*)nmg)[t];
        float4 b4 = ((const float4*)nmb)[t];
        ushort4 o;
        o.x = f2bf(bf2f(u4.x) * g4.x + b4.x);
        o.y = f2bf(bf2f(u4.y) * g4.y + b4.y);
        o.z = f2bf(bf2f(u4.z) * g4.z + b4.z);
        o.w = f2bf(bf2f(u4.w) * g4.w + b4.w);
        ((ushort4*)(xa + (long)r * D))[t] = o;
    } else {
        int rr = r - MX;
        float4 v = ((const float4*)(lat + (long)rr * D))[t];
        float s  = v.x + v.y + v.z + v.w;
        float ss = v.x*v.x + v.y*v.y + v.z*v.z + v.w*v.w;
        block_reduce_2(s, ss, red);
        float mean = s * (1.0f / D);
        float var  = ss * (1.0f / D) - mean * mean;
        float rstd = rsqrtf(var + EPS);
        float4 g4 = ((const float4*)nlg)[t];
        float4 b4 = ((const float4*)nlb)[t];
        ushort4 o;
        o.x = f2bf((v.x - mean) * rstd * g4.x + b4.x);
        o.y = f2bf((v.y - mean) * rstd * g4.y + b4.y);
        o.z = f2bf((v.z - mean) * rstd * g4.z + b4.z);
        o.w = f2bf((v.w - mean) * rstd * g4.w + b4.w);
        ((ushort4*)(la + (long)rr * D))[t] = o;
    }
}

// --------- row-normalize with affine -> bf16 (FFN A operand) ----------------
__global__ __launch_bounds__(256) void rownorm_affine_bf16_kernel(
    const float* __restrict__ in, const float* __restrict__ g,
    const float* __restrict__ b, unsigned short* __restrict__ out)
{
    __shared__ float red[8];
    int r = blockIdx.x;
    int t = threadIdx.x;
    float4 v = ((const float4*)(in + (long)r * D))[t];
    float s  = v.x + v.y + v.z + v.w;
    float ss = v.x*v.x + v.y*v.y + v.z*v.z + v.w*v.w;
    block_reduce_2(s, ss, red);
    float mean = s * (1.0f / D);
    float var  = ss * (1.0f / D) - mean * mean;
    float rstd = rsqrtf(var + EPS);
    float4 g4 = ((const float4*)g)[t];
    float4 b4 = ((const float4*)b)[t];
    ushort4 o;
    o.x = f2bf((v.x - mean) * rstd * g4.x + b4.x);
    o.y = f2bf((v.y - mean) * rstd * g4.y + b4.y);
    o.z = f2bf((v.z - mean) * rstd * g4.z + b4.z);
    o.w = f2bf((v.w - mean) * rstd * g4.w + b4.w);
    ((ushort4*)(out + (long)r * D))[t] = o;
}

// ------------------------ final LN with affine -> out ------------------------
__global__ __launch_bounds__(256) void final_ln_kernel(
    const float* __restrict__ in, const float* __restrict__ g,
    const float* __restrict__ b, float* __restrict__ out)
{
    __shared__ float red[8];
    int r = blockIdx.x;
    int t = threadIdx.x;
    float4 v = ((const float4*)(in + (long)r * D))[t];
    float s  = v.x + v.y + v.z + v.w;
    float ss = v.x*v.x + v.y*v.y + v.z*v.z + v.w*v.w;
    block_reduce_2(s, ss, red);
    float mean = s * (1.0f / D);
    float var  = ss * (1.0f / D) - mean * mean;
    float rstd = rsqrtf(var + EPS);
    float4 g4 = ((const float4*)g)[t];
    float4 b4 = ((const float4*)b)[t];
    float4 o;
    o.x = (v.x - mean) * rstd * g4.x + b4.x;
    o.y = (v.y - mean) * rstd * g4.y + b4.y;
    o.z = (v.z - mean) * rstd * g4.z + b4.z;
    o.w = (v.w - mean) * rstd * g4.w + b4.w;
    ((float4*)(out + (long)r * D))[t] = o;
}

// ---------------------- lat init: broadcast latents to B ---------------------
__global__ __launch_bounds__(256) void lat_init_kernel(
    const float* __restrict__ latents, float* __restrict__ lat)
{
    int r = blockIdx.x;            // b*NL + i
    int i = r % NL;
    int t = threadIdx.x;
    ((float4*)(lat + (long)r * D))[t] = ((const float4*)(latents + (long)i * D))[t];
}

// ---------- weight convert via LDS transpose (coalesced both sides) ----------
// dst per layer: [ wlatT(1536x1024) | woT(1024x512) | f1T(4096x1024) | f2T(1024x4096) ]
constexpr long WL_LAT = 1536L * 1024;
constexpr long WL_WO  = 1024L * 512;
constexpr long WL_F1  = 4096L * 1024;
constexpr long WL_F2  = 1024L * 4096;
constexpr long WL_SZ  = WL_LAT + WL_WO + WL_F1 + WL_F2;   // 10,485,760 ushorts

__device__ __forceinline__ void conv_tile64(
    const float* __restrict__ src, unsigned short* __restrict__ dst,
    int Kd, int Nd, int tn, int tk, float* lds)
{
    int t = threadIdx.x;
    int n0 = tn * 64, k0 = tk * 64;
#pragma unroll
    for (int p = 0; p < 16; ++p) {
        int idx = p * 256 + t;
        int kr = idx >> 6, nc = idx & 63;
        lds[nc * 65 + kr] = src[(long)(k0 + kr) * Nd + n0 + nc];
    }
    __syncthreads();
#pragma unroll
    for (int p = 0; p < 2; ++p) {
        int nl_ = p * 32 + (t >> 3);
        int kc  = t & 7;
        unsigned short u[8];
#pragma unroll
        for (int j = 0; j < 8; ++j)
            u[j] = f2bf(lds[nl_ * 65 + kc * 8 + j]);
        *(uint4*)(dst + (long)(n0 + nl_) * Kd + k0 + kc * 8) = *(uint4*)u;
    }
}

__global__ __launch_bounds__(256) void wt_conv_all_kernel(
    const float* __restrict__ wq, const float* __restrict__ wkv,
    const float* __restrict__ wo, const float* __restrict__ ffw1,
    const float* __restrict__ ffw2,
    unsigned short* __restrict__ wbuf, long wstride, int layer0)
{
    __shared__ float lds[64 * 65];
    int l = layer0 + blockIdx.y;
    unsigned short* wl = wbuf + (long)blockIdx.y * wstride;
    const float* wq_l   = wq   + (long)l * D * INNER;
    const float* wkv_l  = wkv  + (long)l * D * 2 * INNER;
    const float* wo_l   = wo   + (long)l * INNER * D;
    const float* ffw1_l = ffw1 + (long)l * D * 4 * D;
    const float* ffw2_l = ffw2 + (long)l * 4 * D * D;

    int T = blockIdx.x;
    if (T < 128) {
        conv_tile64(wq_l, wl, D, INNER, T & 7, T >> 3, lds);
    } else if (T < 384) {
        int Ti = T - 128;
        conv_tile64(wkv_l, wl + 512L * D, D, 2 * INNER, Ti & 15, Ti >> 4, lds);
    } else if (T < 512) {
        int Ti = T - 384;
        conv_tile64(wo_l, wl + WL_LAT, INNER, D, Ti & 15, Ti >> 4, lds);
    } else if (T < 1536) {
        int Ti = T - 512;
        conv_tile64(ffw1_l, wl + WL_LAT + WL_WO, D, 4 * D, Ti & 63, Ti >> 6, lds);
    } else {
        int Ti = T - 1536;
        conv_tile64(ffw2_l, wl + WL_LAT + WL_WO + WL_F1, 4 * D, D, Ti & 15, Ti >> 4, lds);
    }
}

// --------------------- wave-tile bf16 GEMM core ------------------------------
__device__ __forceinline__ void load_set(
    const unsigned short* __restrict__ ap, const unsigned short* __restrict__ bp,
    long rs, int ko, bf16x8 (&av)[4], bf16x8 (&bv)[4])
{
#pragma unroll
    for (int q = 0; q < 4; ++q) {
        av[q] = *(const bf16x8*)(ap + q * rs + ko);
        bv[q] = *(const bf16x8*)(bp + q * rs + ko);
    }
}

__device__ __forceinline__ void mfma_set(
    const bf16x8 (&av)[4], const bf16x8 (&bv)[4], f32x4 (&acc)[4][4])
{
#pragma unroll
    for (int mm = 0; mm < 4; ++mm)
#pragma unroll
        for (int nn = 0; nn < 4; ++nn)
            acc[mm][nn] = __builtin_amdgcn_mfma_f32_16x16x32_bf16(av[mm], bv[nn], acc[mm][nn], 0, 0, 0);
}

__device__ __forceinline__ void gemm_core(
    const unsigned short* __restrict__ ap, const unsigned short* __restrict__ bp,
    long rs, int Kc, f32x4 (&acc)[4][4])
{
    bf16x8 aC[4], bC[4], aN[4], bN[4];
    load_set(ap, bp, rs, 0, aC, bC);
    for (int ko = 0; ko < Kc; ko += 64) {
        load_set(ap, bp, rs, ko + 32, aN, bN);
        mfma_set(aC, bC, acc);
        if (ko + 64 < Kc)
            load_set(ap, bp, rs, ko + 64, aC, bC);
        mfma_set(aN, bN, acc);
    }
}

// ---------------- fused latent-QKV + x-KV projection (1-wave blocks) ---------
// tiles 0..551: A=la (23m x 24n), Bt=wlatT -> qb / kb(j=F+i) / vt
// tiles 552..1607: A=xa (66m x 16n), Bt=wlatT+512*D -> kb(j=i) / vt
// grid = 1608 (divisible by 8), XCD-chunked.
__global__ __launch_bounds__(64) void qkv_fused_kernel(
    const unsigned short* __restrict__ la, const unsigned short* __restrict__ xa,
    const unsigned short* __restrict__ wlatT,
    unsigned short* __restrict__ qb, unsigned short* __restrict__ kb,
    unsigned short* __restrict__ vt)
{
    int lane = threadIdx.x;
    int lr = lane & 15, lg = lane >> 4;

    const unsigned short* A;
    const unsigned short* Bt;
    long m0, n0;
    int M, rpb, joff, qcols;
    int T = xcd_swz(blockIdx.x, 1608);
    if (T < 552) {
        int bm = T % 23, bn = T / 23;
        A = la; Bt = wlatT;
        m0 = (long)bm * 64; n0 = (long)bn * 64;
        M = MLAT; rpb = NL; joff = F; qcols = 512;
    } else {
        int Ti = T - 552;
        int bm = Ti % 66, bn = Ti / 66;
        A = xa; Bt = wlatT + 512L * D;
        m0 = (long)bm * 64; n0 = (long)bn * 64;
        M = MX; rpb = F; joff = 0; qcols = 0;
    }

    const unsigned short* ap = A  + (m0 + lr) * D + lg * 8;
    const unsigned short* bp = Bt + (n0 + lr) * D + lg * 8;
    f32x4 acc[4][4] = {};
    gemm_core(ap, bp, 16L * D, D, acc);

#pragma unroll
    for (int mm = 0; mm < 4; ++mm) {
        long ar0 = m0 + mm * 16 + lg * 4;
        if (ar0 >= M) continue;
#pragma unroll
        for (int nn = 0; nn < 4; ++nn) {
            long col = n0 + nn * 16 + lr;
            f32x4 v = acc[mm][nn];
            if (col < qcols) {
#pragma unroll
                for (int r = 0; r < 4; ++r) {
                    long ar = ar0 + r;
                    if (ar < M) {
                        int bb = ar >= NL;
                        long i = ar - (bb ? NL : 0);
                        qb[((long)bb * NL_PAD + i) * INNER + col] = f2bf(v[r] * 0.125f);
                    }
                }
            } else {
                int c = (int)col - qcols;    // 0..1023
                if (c < 512) {               // K-part
#pragma unroll
                    for (int r = 0; r < 4; ++r) {
                        long ar = ar0 + r;
                        if (ar < M) {
                            int bb = ar >= rpb;
                            long i = ar - (bb ? rpb : 0);
                            kb[((long)bb * FN_PAD + joff + i) * INNER + c] = f2bf(v[r]);
                        }
                    }
                } else {                     // V-part (transposed store)
                    int d = c - 512;
                    int bb0 = ar0 >= rpb;
                    int bb3 = (ar0 + 3) >= rpb;
                    long i0 = ar0 - (bb0 ? rpb : 0);
                    long j0 = joff + i0;
                    if ((ar0 + 3 < M) && (bb0 == bb3) && ((j0 & 3) == 0)) {
                        ushort4 pk;
                        pk.x = f2bf(v[0]); pk.y = f2bf(v[1]);
                        pk.z = f2bf(v[2]); pk.w = f2bf(v[3]);
                        *(ushort4*)(vt + ((long)bb0 * INNER + d) * FN_PAD + j0) = pk;
                    } else {
#pragma unroll
                        for (int r = 0; r < 4; ++r) {
                            long ar = ar0 + r;
                            if (ar < M) {
                                int bb = ar >= rpb;
                                long i = ar - (bb ? rpb : 0);
                                vt[((long)bb * INNER + d) * FN_PAD + joff + i] = f2bf(v[r]);
                            }
                        }
                    }
                }
            }
        }
    }
}

// ---------- split-K GEMM, 1-wave blocks, flat grid + XCD chunking ------------
#define MODE_RESA  0   // f32 unsafeAtomicAdd into C[ar*ldc+col]
#define MODE_GELU  1   // bf16 C[ar*ldc+col] = gelu(v)

__global__ __launch_bounds__(64) void gemm_split_kernel(
    const unsigned short* __restrict__ A, const unsigned short* __restrict__ Bt,
    void* __restrict__ C, int M, int K, int Kc, int mode, int ldc,
    int bmN, int bnN)
{
    int lane = threadIdx.x;
    int lr = lane & 15, lg = lane >> 4;
    int u = xcd_swz(blockIdx.x, gridDim.x);
    int bm = u % bmN;
    int t2 = u / bmN;
    int bn = t2 % bnN;
    int kz = t2 / bnN;
    long m0 = (long)bm * 64;
    long n0 = (long)bn * 64;
    int k0 = kz * Kc;

    const unsigned short* ap = A  + (m0 + lr) * K + k0 + lg * 8;
    const unsigned short* bp = Bt + (n0 + lr) * K + k0 + lg * 8;
    f32x4 acc[4][4] = {};
    gemm_core(ap, bp, 16L * K, Kc, acc);

#pragma unroll
    for (int mm = 0; mm < 4; ++mm) {
        long ar0 = m0 + mm * 16 + lg * 4;
        if (ar0 >= M) continue;
#pragma unroll
        for (int nn = 0; nn < 4; ++nn) {
            long col = n0 + nn * 16 + lr;
            f32x4 v = acc[mm][nn];
            if (mode == MODE_RESA) {
                float* p = (float*)C;
#pragma unroll
                for (int r = 0; r < 4; ++r)
                    if (ar0 + r < M)
                        unsafeAtomicAdd(&p[(ar0 + r) * (long)ldc + col], v[r]);
            } else {
                unsigned short* p = (unsigned short*)C;
#pragma unroll
                for (int r = 0; r < 4; ++r)
                    if (ar0 + r < M) {
                        float val = v[r];
                        val = 0.5f * val * (1.0f + erff(val * 0.70710678118654752f));
                        p[(ar0 + r) * (long)ldc + col] = f2bf(val);
                    }
            }
        }
    }
}

// ------------- MFMA flash attention, split-KV, flat grid + XCD chunking ------
// flat block id -> (q64, bh, sidx) with q64 fastest: the 12 q-blocks sharing
// one (bh,sidx) K/V slice land on ONE XCD's L2.
__global__ __launch_bounds__(256) void attn_split_kernel(
    const unsigned short* __restrict__ qb, const unsigned short* __restrict__ kb,
    const unsigned short* __restrict__ vt, const int* __restrict__ split,
    float* __restrict__ po, float* __restrict__ pml, int skv)
{
    int u = xcd_swz(blockIdx.x, gridDim.x);
    int q64  = u % 12;
    int bh   = (u / 12) % NBH;
    int sidx = u / (12 * NBH);
    int b  = bh >> 3;
    int h  = bh & 7;
    int w  = threadIdx.x >> 6;
    int lane = threadIdx.x & 63;
    int q0 = q64 * 64 + w * 16;
    if (q0 >= NL) return;

    __shared__ unsigned short p_lds[4][16 * 64];   // 2KB per wave, XOR-swizzled
    unsigned short* pl = p_lds[w];

    int lr = lane & 15;
    int lg = lane >> 4;

    bf16x8 qa0, qa1;
    {
        const unsigned short* qrow = qb + ((long)b * NL_PAD + q0 + lr) * INNER + h * 64;
        qa0 = *(const bf16x8*)(qrow + lg * 8);
        qa1 = *(const bf16x8*)(qrow + 32 + lg * 8);
    }

    f32x4 oacc[4] = {{0,0,0,0},{0,0,0,0},{0,0,0,0},{0,0,0,0}};
    float m[4]    = {-1e30f, -1e30f, -1e30f, -1e30f};
    float lsum[4] = {0.f, 0.f, 0.f, 0.f};

    int sp = split[b];
    if (sp < 0) sp = 0;
    if (sp > F) sp = F;
    int ntx = (sp + 63) >> 6;
    int ntot = ntx + 12;
    int t0 = (ntot * sidx) / skv;
    int t1 = (ntot * (sidx + 1)) / skv;

    for (int t = t0; t < t1; ++t) {
        int j0, limit;
        if (t < ntx) { j0 = t * 64;             limit = sp; }
        else         { j0 = F + (t - ntx) * 64; limit = FN; }

        f32x4 s[4] = {{0,0,0,0},{0,0,0,0},{0,0,0,0},{0,0,0,0}};
        const unsigned short* kbase =
            kb + ((long)b * FN_PAD + j0 + lr) * INNER + h * 64 + lg * 8;
#pragma unroll
        for (int st = 0; st < 4; ++st) {
            bf16x8 kf0 = *(const bf16x8*)(kbase + (long)st * 16 * INNER);
            bf16x8 kf1 = *(const bf16x8*)(kbase + (long)st * 16 * INNER + 32);
            s[st] = __builtin_amdgcn_mfma_f32_16x16x32_bf16(qa0, kf0, s[st], 0, 0, 0);
            s[st] = __builtin_amdgcn_mfma_f32_16x16x32_bf16(qa1, kf1, s[st], 0, 0, 0);
        }

        if (j0 + 64 > limit) {
#pragma unroll
            for (int st = 0; st < 4; ++st) {
                bool valid = (j0 + st * 16 + lr) < limit;
#pragma unroll
                for (int r = 0; r < 4; ++r)
                    s[st][r] = valid ? s[st][r] : -1e30f;
            }
        }

        float tm[4];
#pragma unroll
        for (int r = 0; r < 4; ++r)
            tm[r] = fmaxf(fmaxf(s[0][r], s[1][r]), fmaxf(s[2][r], s[3][r]));
#pragma unroll
        for (int off = 1; off < 16; off <<= 1) {
#pragma unroll
            for (int r = 0; r < 4; ++r)
                tm[r] = fmaxf(tm[r], __shfl_xor(tm[r], off));
        }
        float cr[4];
#pragma unroll
        for (int r = 0; r < 4; ++r) {
            float mn = fmaxf(m[r], tm[r]);
            cr[r] = __expf(m[r] - mn);
            m[r]  = mn;
        }
#pragma unroll
        for (int st = 0; st < 4; ++st)
#pragma unroll
            for (int r = 0; r < 4; ++r)
                s[st][r] = __expf(s[st][r] - m[r]);
        float ts[4];
#pragma unroll
        for (int r = 0; r < 4; ++r)
            ts[r] = (s[0][r] + s[1][r]) + (s[2][r] + s[3][r]);
#pragma unroll
        for (int off = 1; off < 16; off <<= 1) {
#pragma unroll
            for (int r = 0; r < 4; ++r)
                ts[r] += __shfl_xor(ts[r], off);
        }
#pragma unroll
        for (int r = 0; r < 4; ++r)
            lsum[r] = lsum[r] * cr[r] + ts[r];
#pragma unroll
        for (int nst = 0; nst < 4; ++nst)
#pragma unroll
            for (int r = 0; r < 4; ++r)
                oacc[nst][r] *= cr[r];

#pragma unroll
        for (int st = 0; st < 4; ++st)
#pragma unroll
            for (int r = 0; r < 4; ++r) {
                int row  = lg * 4 + r;
                int col  = st * 16 + lr;
                int byte = (row * 128 + col * 2) ^ ((row & 7) << 4);
                *(unsigned short*)((char*)pl + byte) = f2bf(s[st][r]);
            }

#pragma unroll
        for (int kk = 0; kk < 2; ++kk) {
            int row  = lr;
            int byte = (row * 128 + kk * 64 + lg * 16) ^ ((row & 7) << 4);
            bf16x8 pa = *(const bf16x8*)((char*)pl + byte);
#pragma unroll
            for (int nst = 0; nst < 4; ++nst) {
                const unsigned short* vp =
                    vt + ((long)bh * DH + nst * 16 + lr) * FN_PAD + j0 + kk * 32 + lg * 8;
                bf16x8 vf = *(const bf16x8*)vp;
                oacc[nst] = __builtin_amdgcn_mfma_f32_16x16x32_bf16(pa, vf, oacc[nst], 0, 0, 0);
            }
        }
    }

    // ---- store unnormalized partials ----
    long base = ((long)sidx * NBH + bh) * NL_PAD;
#pragma unroll
    for (int nst = 0; nst < 4; ++nst)
#pragma unroll
        for (int r = 0; r < 4; ++r) {
            int row = q0 + lg * 4 + r;
            if (row < NL)
                po[(base + row) * DH + nst * 16 + lr] = oacc[nst][r];
        }
    if (lr == 0) {
#pragma unroll
        for (int r = 0; r < 4; ++r) {
            int row = q0 + lg * 4 + r;
            if (row < NL) {
                pml[(base + row) * 2 + 0] = m[r];
                pml[(base + row) * 2 + 1] = lsum[r];
            }
        }
    }
}

// -------- combine skv partials -> ob bf16 (one wave per (b,h,i) row) --------
__global__ __launch_bounds__(256) void attn_combine_kernel(
    const float* __restrict__ po, const float* __restrict__ pml,
    unsigned short* __restrict__ o, int skv)
{
    int row = blockIdx.x * 4 + (threadIdx.x >> 6);
    if (row >= NBH * NL) return;
    int lane = threadIdx.x & 63;
    int bh = row / NL;
    int i  = row - bh * NL;
    int b = bh >> 3, h = bh & 7;

    float m = -1e30f, l = 0.0f, acc = 0.0f;
    for (int s = 0; s < skv; ++s) {
        long base = ((long)s * NBH + bh) * NL_PAD + i;
        float ms = pml[base * 2 + 0];
        float ls = pml[base * 2 + 1];
        float os = po[base * DH + lane];
        float mn = fmaxf(m, ms);
        float c1 = __expf(m - mn);
        float c2 = __expf(ms - mn);
        acc = acc * c1 + os * c2;
        l   = l * c1 + ls * c2;
        m   = mn;
    }
    o[((long)b * NL + i) * INNER + h * 64 + lane] = f2bf(acc / l);
}

// ------------------------------- host side ----------------------------------
extern "C" void kernel_launch(void* const* d_in, const int* in_sizes, int n_in,
                              void* d_out, int out_size, void* d_ws, size_t ws_size,
                              hipStream_t stream)
{
    const float* x        = (const float*)d_in[0];
    const int*   split    = (const int*)d_in[1];
    const float* latents  = (const float*)d_in[2];
    const float* sp_emb   = (const float*)d_in[3];
    const float* fr_emb   = (const float*)d_in[4];
    const float* nm_g     = (const float*)d_in[5];
    const float* nm_b     = (const float*)d_in[6];
    const float* nl_g     = (const float*)d_in[7];
    const float* nl_b     = (const float*)d_in[8];
    const float* wq       = (const float*)d_in[9];
    const float* wkv      = (const float*)d_in[10];
    const float* wo       = (const float*)d_in[11];
    const float* ffn_g    = (const float*)d_in[12];
    const float* ffn_b    = (const float*)d_in[13];
    const float* ffw1     = (const float*)d_in[14];
    const float* ffw2     = (const float*)d_in[15];
    const float* final_g  = (const float*)d_in[16];
    const float* final_b  = (const float*)d_in[17];
    float* out = (float*)d_out;

    // ---- cursor-based workspace layout ----
    char* cur = (char*)d_ws;
    auto alloc = [&](size_t bytes) {
        void* p = (void*)cur;
        cur += (bytes + 255) & ~(size_t)255;
        return p;
    };

    unsigned short* xhat = (unsigned short*)alloc((long)MX * D * 2);
    float* lat  = (float*)alloc((long)B * NL * D * 4);
    unsigned short* la  = (unsigned short*)alloc((long)MLAT_PAD * D * 2);
    unsigned short* fa  = (unsigned short*)alloc((long)MLAT_PAD * D * 2);
    unsigned short* h1b = (unsigned short*)alloc((long)MLAT_PAD * 4 * D * 2);
    unsigned short* ob  = (unsigned short*)alloc((long)MLAT_PAD * INNER * 2);
    unsigned short* qb  = (unsigned short*)alloc((long)B * NL_PAD * INNER * 2);
    unsigned short* kb  = (unsigned short*)alloc((long)B * FN_PAD * INNER * 2);
    unsigned short* vt  = (unsigned short*)alloc((long)B * FN_PAD * INNER * 2);
    unsigned short* xa  = (unsigned short*)alloc((long)MX * D * 2);
    float* pml = (float*)alloc((long)SKVMAX * NBH * NL_PAD * 2 * 4);

    size_t fixed = (size_t)(cur - (char*)d_ws);
    const size_t po8 = ((size_t)8 * NBH * NL_PAD * DH * 4 + 255) & ~(size_t)255;
    const size_t po4 = ((size_t)4 * NBH * NL_PAD * DH * 4 + 255) & ~(size_t)255;
    const size_t wb6 = ((size_t)6 * WL_SZ * 2 + 255) & ~(size_t)255;
    const size_t wb1 = ((size_t)WL_SZ * 2 + 255) & ~(size_t)255;
    const size_t margin = 4096;

    int skv;
    bool hoist_w;
    if (fixed + po8 + wb6 + margin <= ws_size)      { skv = 8; hoist_w = true;  }
    else if (fixed + po4 + wb6 + margin <= ws_size) { skv = 4; hoist_w = true;  }
    else if (fixed + po8 + wb1 + margin <= ws_size) { skv = 8; hoist_w = false; }
    else                                            { skv = 4; hoist_w = false; }

    float* po = (float*)alloc(skv == 8 ? po8 : po4);
    unsigned short* wbuf = (unsigned short*)alloc(hoist_w ? wb6 : wb1);

    emb_ln_kernel<<<MX, 256, 0, stream>>>(x, sp_emb, fr_emb, xhat);
    lat_init_kernel<<<B * NL, 256, 0, stream>>>(latents, lat);

    if (hoist_w)
        wt_conv_all_kernel<<<dim3(2560, 6), 256, 0, stream>>>(
            wq, wkv, wo, ffw1, ffw2, wbuf, WL_SZ, 0);

    for (int l = 0; l < DEPTH; ++l) {
        unsigned short* wl = wbuf + (hoist_w ? (long)l * WL_SZ : 0);
        if (!hoist_w)
            wt_conv_all_kernel<<<dim3(2560, 1), 256, 0, stream>>>(
                wq, wkv, wo, ffw1, ffw2, wbuf, 0, l);

        unsigned short* wlatT = wl;
        unsigned short* woT   = wl + WL_LAT;
        unsigned short* f1T   = wl + WL_LAT + WL_WO;
        unsigned short* f2T   = wl + WL_LAT + WL_WO + WL_F1;

        // xa = xhat*nm+b ; la = LN(lat)*nl+b   (one dispatch)
        prep_a_kernel<<<MX + MLAT, 256, 0, stream>>>(
            xhat, lat, nm_g + (long)l * D, nm_b + (long)l * D,
            nl_g + (long)l * D, nl_b + (long)l * D, xa, la);

        // fused q/kv(lat) + kv(x): 1608 one-wave blocks, XCD-chunked
        qkv_fused_kernel<<<1608, 64, 0, stream>>>(la, xa, wlatT, qb, kb, vt);

        // attention: split-KV partials (flat grid, XCD-chunked) + combine
        attn_split_kernel<<<12 * NBH * skv, 256, 0, stream>>>(
            qb, kb, vt, split, po, pml, skv);
        attn_combine_kernel<<<(NBH * NL + 3) / 4, 256, 0, stream>>>(po, pml, ob, skv);

        // lat += ob @ wo   (split-K = 4, one-wave blocks, XCD-chunked)
        gemm_split_kernel<<<23 * 16 * 4, 64, 0, stream>>>(
            ob, woT, lat, MLAT, INNER, 128, MODE_RESA, D, 23, 16);

        // FFN
        rownorm_affine_bf16_kernel<<<MLAT, 256, 0, stream>>>(
            lat, ffn_g + (long)l * D, ffn_b + (long)l * D, fa);
        gemm_split_kernel<<<23 * 64, 64, 0, stream>>>(
            fa, f1T, h1b, MLAT, D, D, MODE_GELU, 4 * D, 23, 64);
        gemm_split_kernel<<<23 * 16 * 8, 64, 0, stream>>>(
            h1b, f2T, lat, MLAT, 4 * D, 512, MODE_RESA, D, 23, 16);
    }

    final_ln_kernel<<<MLAT, 256, 0, stream>>>(lat, final_g, final_b, out);
}